// Round 6
// baseline (148.988 us; speedup 1.0000x reference)
//
#include <hip/hip_runtime.h>

#define N_ANCHORS 5000
#define N_CLASSES 80
#define OUT_COLS  84
#define MAX_BOXES 300
#define SCORE_THR 0.05f

#define SORT_PAD  5056
#define SIDX_PAD  5120
#define NB        4096
#define SLOTS     8
#define DONEP     0x40000000
#define NIW       3            // scan: intra workers wv 1..3
#define NSW       4            // scan: sweeps wv 4..7

typedef unsigned long long u64;
typedef unsigned int u32;
typedef unsigned short u16;

#define WG __HIP_MEMORY_SCOPE_WORKGROUP

__device__ __forceinline__ float readlane_f(float v, int l) {
    return __int_as_float(__builtin_amdgcn_readlane(__float_as_int(v), l));
}
__device__ __forceinline__ u64 aload64(u64* p) {
    return __hip_atomic_load(p, __ATOMIC_ACQUIRE, WG);
}
// monotone score->bucket map; mirrored so chunk 0 = HIGHEST scores
__device__ __forceinline__ int bucket_of(float s) {
    float u = sqrtf(s);
    int b = (int)((u - 0.2236f) * 5275.0f);
    return (NB - 1) - min(max(b, 0), NB - 1);
}
// IoU(a,q) > 0.5  <=>  3*inter > aa+aq.  Single clamp: all real areas >= 1
// so aa+aq > 0; if ih < 0 then iw_cl*ih <= 0 < aa+aq -> false.  Sentinel q
// (1e9 coords, karea 1e18) -> false (iw*ih bounded by ~6.4e11 << 1e18).
__device__ __forceinline__ bool iou3(float4 a, float aa, float4 q, float aq) {
    float iw = fmaxf(fminf(a.z, q.z) - fmaxf(a.x, q.x), 0.0f);
    float ih = fminf(a.w, q.w) - fmaxf(a.y, q.y);
    return 3.0f * (iw * ih) > aa + aq;
}

// ============ dispatch 1: prep + bucket sort -> workspace ============
// LDS: lk[5056]u64 @0 | hist[4096]u32 @40448 | wtot 16 u32 @56832
__global__ __launch_bounds__(1024) void nms_sort(const float* __restrict__ cls,
                                                 const float* __restrict__ boxesf,
                                                 float* __restrict__ out,
                                                 u16* __restrict__ sidx,
                                                 u32* __restrict__ totals) {
    __shared__ __align__(16) char SMEM[56896];
    u64* lk   = (u64*)SMEM;
    u32* hist = (u32*)(SMEM + 40448);
    u32* wtot = (u32*)(SMEM + 56832);

    const int c = blockIdx.x;
    const int t = threadIdx.x;
    const int lane = t & 63;
    const int wv = t >> 6;

    // prep: strided score loads + race-free out init
    u32 sb[5];
    #pragma unroll
    for (int m = 0; m < 5; ++m) {
        int j = m * 1024 + t;
        float v = (j < N_ANCHORS) ? cls[(size_t)j * N_CLASSES + c] : 0.0f;
        sb[m] = (v > SCORE_THR) ? __float_as_uint(v) : 0u;
    }
    for (int i = t; i < N_ANCHORS; i += 1024)
        out[(size_t)i * OUT_COLS + 4 + c] = 0.0f;
    if (c < 4)
        for (int i = t; i < N_ANCHORS; i += 1024)
            out[(size_t)i * OUT_COLS + c] = boxesf[(size_t)i * 4 + c];

    for (int b = t; b < NB; b += 1024) hist[b] = 0u;
    __syncthreads();
    #pragma unroll
    for (int m = 0; m < 5; ++m)
        if (sb[m]) atomicAdd(&hist[bucket_of(__uint_as_float(sb[m]))], 1u);
    __syncthreads();

    const int hbase = t * 4;
    u32 vals[4]; u32 run = 0;
    #pragma unroll
    for (int k = 0; k < 4; ++k) { run += hist[hbase + k]; vals[k] = run; }
    u32 x = run;
    #pragma unroll
    for (int off = 1; off < 64; off <<= 1) { u32 y = __shfl_up(x, off); if (lane >= off) x += y; }
    if (lane == 63) wtot[wv] = x;
    __syncthreads();
    u32 woff = 0;
    for (int w = 0; w < wv; ++w) woff += wtot[w];
    const u32 exb = woff + x - run;
    #pragma unroll
    for (int k = 0; k < 4; ++k) hist[hbase + k] = exb + (k ? vals[k - 1] : 0u);
    __syncthreads();
    #pragma unroll
    for (int m = 0; m < 5; ++m) {
        if (sb[m]) {
            int j = m * 1024 + t;
            u32 pos = atomicAdd(&hist[bucket_of(__uint_as_float(sb[m]))], 1u);
            lk[pos] = ((u64)sb[m] << 32) | (u32)(~(u32)j);
        }
    }
    __syncthreads();
    const int total = (int)hist[NB - 1];
    for (int v = total + t; v < SORT_PAD; v += 1024) lk[v] = 0ull;
    for (int b = hbase; b < hbase + 4; ++b) {
        int s0 = b ? (int)hist[b - 1] : 0;
        int e  = (int)hist[b];
        for (int i = s0 + 1; i < e; ++i) {
            u64 key = lk[i]; int q = i - 1;
            while (q >= s0 && lk[q] < key) { lk[q + 1] = lk[q]; --q; }
            lk[q + 1] = key;
        }
    }
    __syncthreads();
    // export sorted anchor indices (u16, 0xFFFF sentinel)
    u16* sc_ = sidx + (size_t)c * SIDX_PAD;
    for (int v = t; v < SIDX_PAD; v += 1024) {
        u64 e = (v < SORT_PAD) ? lk[v] : 0ull;
        sc_[v] = e ? (u16)(~(u32)e) : (u16)0xFFFF;
    }
    if (t == 0) totals[c] = (u32)total;
}

// ============ dispatch 2: pipelined scan (8 waves) ============
// LDS: Iring 8*64 u64 @0 | Bring 8*64 f4 @4096 | kbox 304 f4 @12288
// | karea 304 f32 @17152 | kout16 304 u16 @18368 | KS 8 u64 @18976
// | KBa 8 u32 @19040 | flagIK 8 u64 @19072 {lo=flagK,hi=flagI} | progcnt @19136
__global__ __launch_bounds__(512, 1) void nms_scan(const float* __restrict__ cls,
                                                   const float4* __restrict__ boxes4,
                                                   const u16* __restrict__ sidx,
                                                   const u32* __restrict__ totals,
                                                   float* __restrict__ out) {
    __shared__ __align__(16) char SMEM[19200];
    u64*    Iring   = (u64*)SMEM;
    float4* Bring   = (float4*)(SMEM + 4096);
    float4* kbox    = (float4*)(SMEM + 12288);   // 304 slots, sentinel-padded
    float*  karea   = (float*)(SMEM + 17152);    // kept areas, sentinel 1e18
    u16*    kout16  = (u16*)(SMEM + 18368);
    u64*    KS      = (u64*)(SMEM + 18976);
    u32*    KBa     = (u32*)(SMEM + 19040);
    u64*    flagIK  = (u64*)(SMEM + 19072);
    u32*    flagIK32= (u32*)(SMEM + 19072);
    u64*    progcnt = (u64*)(SMEM + 19136);

    const int c = blockIdx.x;
    const int t = threadIdx.x;
    const int lane = t & 63;
    const int wv = t >> 6;
    const u16* sc_ = sidx + (size_t)c * SIDX_PAD;

    if (t < 304) { kbox[t] = make_float4(1e9f, 1e9f, 1e9f, 1e9f); karea[t] = 1e18f; }
    if (t < SLOTS) flagIK[t] = 0ull;
    if (t == 0) *progcnt = 0ull;
    __syncthreads();
    const int total = (int)totals[c];
    const int nch = (total + 63) >> 6;

    if (wv >= 1 && wv <= NIW) {
        // ======= intra workers: 64x64 IoU matrix; compute PRE-gate =======
        for (int j = wv - 1; j < nch; j += NIW) {
            const int slot = j & (SLOTS - 1);
            u16 g = sc_[j * 64 + lane];
            u32 jj = (g != 0xFFFF) ? g : 0u;
            float4 bx = boxes4[jj];
            float ar = (bx.z - bx.x) * (bx.w - bx.y);
            u64 word = 0ull;
            #pragma unroll 16
            for (int q = 0; q < 64; ++q) {
                float4 o;
                o.x = readlane_f(bx.x, q); o.y = readlane_f(bx.y, q);
                o.z = readlane_f(bx.z, q); o.w = readlane_f(bx.w, q);
                float aq = readlane_f(ar, q);
                float iw = fmaxf(fminf(bx.z, o.z) - fmaxf(bx.x, o.x), 0.0f);
                float ih = fminf(bx.w, o.w) - fmaxf(bx.y, o.y);
                if (3.0f * (iw * ih) > ar + aq) word |= (1ull << q);
            }
            u32 p;
            for (;;) {                                   // gate guards the store only
                p = (u32)aload64(progcnt);
                if ((int)p >= j - (SLOTS - 1)) break;
                __builtin_amdgcn_s_sleep(2);
            }
            if (p >= DONEP) return;
            Iring[slot * 64 + lane] = word;
            if (lane == 0)
                __hip_atomic_store(&flagIK32[slot * 2 + 1], (u32)(j + 1), __ATOMIC_RELEASE, WG);
        }
        return;
    }
    if (wv > NIW) {
        // ======= sweeps: incremental refresh vs packed {prog,kcnt} =======
        for (int j = wv - (NIW + 1); j < nch; j += NSW) {
            const int slot = j & (SLOTS - 1);
            u16 g = sc_[j * 64 + lane];
            bool validL = (g != 0xFFFF);
            u32 jj = validL ? g : 0u;
            float4 bx = boxes4[jj];
            float ar = (bx.z - bx.x) * (bx.w - bx.y);
            u64 pk;
            for (;;) {                                   // slot-free gate
                pk = aload64(progcnt);
                if ((int)(u32)pk >= j - (SLOTS - 1)) break;
                __builtin_amdgcn_s_sleep(2);
            }
            if ((u32)pk >= DONEP) return;
            Bring[slot * 64 + lane] = bx;
            bool sup = !validL;                          // invalid = suppressed
            u32 done = 0; bool alldead = false;
            for (;;) {
                u32 kn = (u32)(pk >> 32);
                u32 r4 = kn & ~3u;                       // bulk rounds DOWN: only
                for (u32 r = done; r < r4; r += 4) {     // published entries read
                    float4 q0 = kbox[r], q1 = kbox[r+1], q2 = kbox[r+2], q3 = kbox[r+3];
                    float4 a4 = *(const float4*)(karea + r);
                    sup = sup | iou3(bx,ar,q0,a4.x) | iou3(bx,ar,q1,a4.y)
                              | iou3(bx,ar,q2,a4.z) | iou3(bx,ar,q3,a4.w);
                    if (((r >> 2) & 7u) == 7u && !__ballot(!sup)) { alldead = true; break; }
                }
                if (alldead) break;
                for (u32 r = r4; r < kn; ++r)            // <=3 published remainder
                    sup = sup | iou3(bx, ar, kbox[r], karea[r]);
                done = r4;
                if ((int)(u32)pk >= j - 2) break;        // coverage fresh enough
                __builtin_amdgcn_s_sleep(1);
                pk = aload64(progcnt);
            }
            u64 ksf = __ballot(sup);
            if (lane == 0) {
                KS[slot] = ksf; KBa[slot] = (u32)(pk >> 32);
                __hip_atomic_store(&flagIK32[slot * 2], (u32)(j + 1), __ATOMIC_RELEASE, WG);
            }
            if ((u32)pk >= DONEP) return;
        }
        return;
    }

    // ======= wave 0: serial scan (high prio; shares SIMD with 1 wave now) =======
    __builtin_amdgcn_s_setprio(3);
    int kept = 0; u32 kcur = 0; bool capped = false;
    u16 key = (nch > 0) ? sc_[lane] : (u16)0xFFFF;       // chunk-0 prefetch
    for (int k = 0; k < nch; ++k) {
        const int slot = k & (SLOTS - 1);
        bool valid = (key != 0xFFFF);
        u32 j = valid ? key : 0u;

        const u64 want = ((u64)(u32)(k + 1) << 32) | (u32)(k + 1);
        while (aload64(&flagIK[slot]) != want) { }        // both flags, one poll
        u64 ks = KS[slot];
        u32 kb = KBa[slot];
        float4 bx = Bring[slot * 64 + lane];
        u64 I = Iring[slot * 64 + lane];
        if (ks != ~0ull) {
            float ar = (bx.z - bx.x) * (bx.w - bx.y);
            bool alive = valid && !((ks >> lane) & 1ull);
            u32 r1 = (kcur + 3) & ~3u;                    // own writes: race-free
            for (u32 r = kb & ~3u; r < r1; r += 4) {
                float4 q0 = kbox[r], q1 = kbox[r + 1], q2 = kbox[r + 2], q3 = kbox[r + 3];
                float4 a4 = *(const float4*)(karea + r);
                bool s = iou3(bx, ar, q0, a4.x) | iou3(bx, ar, q1, a4.y)
                       | iou3(bx, ar, q2, a4.z) | iou3(bx, ar, q3, a4.w);
                alive = alive && !s;
            }
            u64 rem = __ballot(alive);
            if (rem) {
                u64 km = 0ull;
                while (rem) {                             // SALU keep chain
                    int pos = __ffsll((long long)rem) - 1;
                    km |= 1ull << pos;
                    if (++kept == MAX_BOXES) { capped = true; break; }
                    u32 lo = (u32)__builtin_amdgcn_readlane((int)(u32)I, pos);
                    u32 hi = (u32)__builtin_amdgcn_readlane((int)(u32)(I >> 32), pos);
                    rem &= ~(((u64)hi << 32) | (u64)lo);  // diag bit kills pos
                }
                if ((km >> lane) & 1ull) {
                    int rank = (int)__popcll(km & ((1ull << lane) - 1ull));
                    kbox[kcur + rank] = bx;
                    karea[kcur + rank] = ar;
                    kout16[kcur + rank] = (u16)j;
                }
                kcur += (u32)__popcll(km);
            }
        }
        if (capped) break;
        if (lane == 0)                                    // single packed release
            __hip_atomic_store(progcnt, ((u64)kcur << 32) | (u32)(k + 1),
                               __ATOMIC_RELEASE, WG);
        if (k + 1 < nch) key = sc_[(k + 1) * 64 + lane];  // prefetch next chunk
    }
    if (lane == 0)
        __hip_atomic_store(progcnt, ((u64)kcur << 32) | DONEP, __ATOMIC_RELEASE, WG);
    __builtin_amdgcn_s_setprio(0);

    // flush: gather scores for kept anchors only (~kcur per class)
    for (u32 i = (u32)lane; i < kcur; i += 64) {
        u32 idx = kout16[i];
        out[(size_t)idx * OUT_COLS + 4 + c] = cls[(size_t)idx * N_CLASSES + c];
    }
}

extern "C" void kernel_launch(void* const* d_in, const int* in_sizes, int n_in,
                              void* d_out, int out_size, void* d_ws, size_t ws_size,
                              hipStream_t stream) {
    const float* boxes = (const float*)d_in[0];
    const float* cls   = (const float*)d_in[1];
    float* out = (float*)d_out;
    u16* sidx   = (u16*)d_ws;                                  // 0.82 MB
    u32* totals = (u32*)((char*)d_ws + N_CLASSES * SIDX_PAD * 2);
    nms_sort<<<N_CLASSES, 1024, 0, stream>>>(cls, boxes, out, sidx, totals);
    nms_scan<<<N_CLASSES, 512, 0, stream>>>(cls, (const float4*)boxes, sidx, totals, out);
}

// Round 8
// 144.596 us; speedup vs baseline: 1.0304x; 1.0304x over previous
//
#include <hip/hip_runtime.h>

#define N_ANCHORS 5000
#define N_CLASSES 80
#define OUT_COLS  84
#define MAX_BOXES 300
#define SCORE_THR 0.05f

#define SORT_PAD  5056
#define SIDX_PAD  5120
#define NB        4096
#define SLOTS     8
#define DONEP     0x40000000
#define NIW       2            // scan: intra workers wv 1..2
#define NSW       5            // scan: sweeps wv 3..7

typedef unsigned long long u64;
typedef unsigned int u32;
typedef unsigned short u16;

#define WG __HIP_MEMORY_SCOPE_WORKGROUP
// hist index padding: breaks the stride-4 8-way bank conflict (4t+(t>>3) covers
// all 32 banks per half-wave)
#define HP(b) ((b) + ((b) >> 5))

__device__ __forceinline__ float readlane_f(float v, int l) {
    return __int_as_float(__builtin_amdgcn_readlane(__float_as_int(v), l));
}
__device__ __forceinline__ u64 aload64(u64* p) {
    return __hip_atomic_load(p, __ATOMIC_ACQUIRE, WG);
}
// monotone score->bucket map; mirrored so chunk 0 = HIGHEST scores
__device__ __forceinline__ int bucket_of(float s) {
    float u = sqrtf(s);
    int b = (int)((u - 0.2236f) * 5275.0f);
    return (NB - 1) - min(max(b, 0), NB - 1);
}
// IoU(a,q) > 0.5  <=>  3*inter > aa+aq.  Single clamp: all real areas >= 1
// so aa+aq > 0; if ih < 0 then iw_cl*ih <= 0 < aa+aq -> false.  Sentinel q
// (1e9 coords, karea 1e18) -> false (iw*ih bounded by ~6.4e11 << 1e18).
__device__ __forceinline__ bool iou3(float4 a, float aa, float4 q, float aq) {
    float iw = fmaxf(fminf(a.z, q.z) - fmaxf(a.x, q.x), 0.0f);
    float ih = fminf(a.w, q.w) - fmaxf(a.y, q.y);
    return 3.0f * (iw * ih) > aa + aq;
}

// ============ dispatch 1: prep + bucket sort -> workspace ============
// LDS: lk[5056]u64 @0 | histp[4224]u32 @40448 | wtot 16 u32 @57344
__global__ __launch_bounds__(1024) void nms_sort(const float* __restrict__ cls,
                                                 const float* __restrict__ boxesf,
                                                 float* __restrict__ out,
                                                 u16* __restrict__ sidx,
                                                 u32* __restrict__ totals) {
    __shared__ __align__(16) char SMEM[57408];
    u64* lk   = (u64*)SMEM;
    u32* hist = (u32*)(SMEM + 40448);
    u32* wtot = (u32*)(SMEM + 57344);

    const int c = blockIdx.x;
    const int t = threadIdx.x;
    const int lane = t & 63;
    const int wv = t >> 6;

    // strided score loads (cls L2-resident; each line feeds 16 class-blocks)
    u32 sb[5];
    #pragma unroll
    for (int m = 0; m < 5; ++m) {
        int j = m * 1024 + t;
        float v = (j < N_ANCHORS) ? cls[(size_t)j * N_CLASSES + c] : 0.0f;
        sb[m] = (v > SCORE_THR) ? __float_as_uint(v) : 0u;
    }
    // coalesced full-row out init: block c owns rows [c*63, c*63+63)
    {
        const int r0 = c * 63;
        const int rend = min(r0 + 63, N_ANCHORS);
        const int nel = (rend - r0) * OUT_COLS;
        float* ob = out + (size_t)r0 * OUT_COLS;
        for (int i = t; i < nel; i += 1024) {
            int row = r0 + i / OUT_COLS;
            int col = i - (i / OUT_COLS) * OUT_COLS;
            ob[i] = (col < 4) ? boxesf[(size_t)row * 4 + col] : 0.0f;
        }
    }

    for (int b = t; b < HP(NB - 1) + 1; b += 1024) hist[b] = 0u;
    __syncthreads();
    #pragma unroll
    for (int m = 0; m < 5; ++m)
        if (sb[m]) atomicAdd(&hist[HP(bucket_of(__uint_as_float(sb[m])))], 1u);
    __syncthreads();

    const int hbase = t * 4;
    u32 vals[4]; u32 run = 0;
    #pragma unroll
    for (int k = 0; k < 4; ++k) { run += hist[HP(hbase + k)]; vals[k] = run; }
    u32 x = run;
    #pragma unroll
    for (int off = 1; off < 64; off <<= 1) { u32 y = __shfl_up(x, off); if (lane >= off) x += y; }
    if (lane == 63) wtot[wv] = x;
    __syncthreads();
    u32 woff = 0;
    for (int w = 0; w < wv; ++w) woff += wtot[w];
    const u32 exb = woff + x - run;
    #pragma unroll
    for (int k = 0; k < 4; ++k) hist[HP(hbase + k)] = exb + (k ? vals[k - 1] : 0u);
    __syncthreads();
    #pragma unroll
    for (int m = 0; m < 5; ++m) {
        if (sb[m]) {
            int j = m * 1024 + t;
            u32 pos = atomicAdd(&hist[HP(bucket_of(__uint_as_float(sb[m])))], 1u);
            lk[pos] = ((u64)sb[m] << 32) | (u32)(~(u32)j);
        }
    }
    __syncthreads();
    const int total = (int)hist[HP(NB - 1)];
    for (int v = total + t; v < SORT_PAD; v += 1024) lk[v] = 0ull;
    for (int b = hbase; b < hbase + 4; ++b) {
        int s0 = b ? (int)hist[HP(b - 1)] : 0;
        int e  = (int)hist[HP(b)];
        for (int i = s0 + 1; i < e; ++i) {
            u64 key = lk[i]; int q = i - 1;
            while (q >= s0 && lk[q] < key) { lk[q + 1] = lk[q]; --q; }
            lk[q + 1] = key;
        }
    }
    __syncthreads();
    // export sorted anchor indices (u16, 0xFFFF sentinel)
    u16* sc_ = sidx + (size_t)c * SIDX_PAD;
    for (int v = t; v < SIDX_PAD; v += 1024) {
        u64 e = (v < SORT_PAD) ? lk[v] : 0ull;
        sc_[v] = e ? (u16)(~(u32)e) : (u16)0xFFFF;
    }
    if (t == 0) totals[c] = (u32)total;
}

// ============ dispatch 2: pipelined scan (8 waves: 1 serial + 2 intra + 5 sweep) ============
// LDS: Iring 8*64 u64 @0 | Bring 8*64 f4 @4096 | kbox 304 f4 @12288
// | karea 304 f32 @17152 | kout16 304 u16 @18368 | KS 8 u64 @18976
// | KBa 8 u32 @19040 | flagIK 8 u64 @19072 {lo=flagK,hi=flagI} | progcnt @19136
__global__ __launch_bounds__(512, 1) void nms_scan(const float* __restrict__ cls,
                                                   const float4* __restrict__ boxes4,
                                                   const u16* __restrict__ sidx,
                                                   const u32* __restrict__ totals,
                                                   float* __restrict__ out) {
    __shared__ __align__(16) char SMEM[19200];
    u64*    Iring   = (u64*)SMEM;
    float4* Bring   = (float4*)(SMEM + 4096);
    float4* kbox    = (float4*)(SMEM + 12288);   // 304 slots, sentinel-padded
    float*  karea   = (float*)(SMEM + 17152);    // kept areas, sentinel 1e18
    u16*    kout16  = (u16*)(SMEM + 18368);
    u64*    KS      = (u64*)(SMEM + 18976);
    u32*    KBa     = (u32*)(SMEM + 19040);
    u64*    flagIK  = (u64*)(SMEM + 19072);
    u32*    flagIK32= (u32*)(SMEM + 19072);
    u64*    progcnt = (u64*)(SMEM + 19136);

    const int c = blockIdx.x;
    const int t = threadIdx.x;
    const int lane = t & 63;
    const int wv = t >> 6;
    const u16* sc_ = sidx + (size_t)c * SIDX_PAD;

    if (t < 304) { kbox[t] = make_float4(1e9f, 1e9f, 1e9f, 1e9f); karea[t] = 1e18f; }
    if (t < SLOTS) flagIK[t] = 0ull;
    if (t == 0) *progcnt = 0ull;
    __syncthreads();
    const int total = (int)totals[c];
    const int nch = (total + 63) >> 6;

    if (wv >= 1 && wv <= NIW) {
        // ======= intra workers: 64x64 IoU matrix; compute PRE-gate =======
        for (int j = wv - 1; j < nch; j += NIW) {
            const int slot = j & (SLOTS - 1);
            u16 g = sc_[j * 64 + lane];
            u32 jj = (g != 0xFFFF) ? g : 0u;
            float4 bx = boxes4[jj];
            float ar = (bx.z - bx.x) * (bx.w - bx.y);
            u64 word = 0ull;
            #pragma unroll 16
            for (int q = 0; q < 64; ++q) {
                float4 o;
                o.x = readlane_f(bx.x, q); o.y = readlane_f(bx.y, q);
                o.z = readlane_f(bx.z, q); o.w = readlane_f(bx.w, q);
                float aq = readlane_f(ar, q);
                float iw = fmaxf(fminf(bx.z, o.z) - fmaxf(bx.x, o.x), 0.0f);
                float ih = fminf(bx.w, o.w) - fmaxf(bx.y, o.y);
                if (3.0f * (iw * ih) > ar + aq) word |= (1ull << q);
            }
            u32 p;
            for (;;) {                                   // gate guards the store only
                p = (u32)aload64(progcnt);
                if ((int)p >= j - (SLOTS - 1)) break;
                __builtin_amdgcn_s_sleep(2);
            }
            if (p >= DONEP) return;
            Iring[slot * 64 + lane] = word;
            if (lane == 0)
                __hip_atomic_store(&flagIK32[slot * 2 + 1], (u32)(j + 1), __ATOMIC_RELEASE, WG);
        }
        return;
    }
    if (wv > NIW) {
        // ======= sweeps: 8-keep unrolled batched-load kept-scan =======
        for (int j = wv - (NIW + 1); j < nch; j += NSW) {
            const int slot = j & (SLOTS - 1);
            u16 g = sc_[j * 64 + lane];
            bool validL = (g != 0xFFFF);
            u32 jj = validL ? g : 0u;
            float4 bx = boxes4[jj];
            float ar = (bx.z - bx.x) * (bx.w - bx.y);
            u64 pk;
            for (;;) {                                   // slot-free gate
                pk = aload64(progcnt);
                if ((int)(u32)pk >= j - (SLOTS - 1)) break;
                __builtin_amdgcn_s_sleep(2);
            }
            if ((u32)pk >= DONEP) return;
            Bring[slot * 64 + lane] = bx;
            bool sup = !validL;                          // invalid = suppressed
            u32 done = 0; bool alldead = false;
            for (;;) {
                u32 kn = (u32)(pk >> 32);
                u32 r8 = kn & ~7u;                       // bulk rounds DOWN: only
                for (u32 r = done; r < r8; r += 8) {     // published entries read
                    // 10 independent b128 loads issued up-front: latency -> throughput
                    float4 q0 = kbox[r+0], q1 = kbox[r+1], q2 = kbox[r+2], q3 = kbox[r+3];
                    float4 q4 = kbox[r+4], q5 = kbox[r+5], q6 = kbox[r+6], q7 = kbox[r+7];
                    float4 a40 = *(const float4*)(karea + r);
                    float4 a41 = *(const float4*)(karea + r + 4);
                    sup = sup | iou3(bx,ar,q0,a40.x) | iou3(bx,ar,q1,a40.y)
                              | iou3(bx,ar,q2,a40.z) | iou3(bx,ar,q3,a40.w)
                              | iou3(bx,ar,q4,a41.x) | iou3(bx,ar,q5,a41.y)
                              | iou3(bx,ar,q6,a41.z) | iou3(bx,ar,q7,a41.w);
                    if (((r >> 3) & 3u) == 3u && !__ballot(!sup)) { alldead = true; break; }
                }
                if (alldead) break;
                u32 d2 = (r8 > done) ? r8 : done;
                for (u32 r = d2; r < kn; ++r)            // <=7 published remainder
                    sup = sup | iou3(bx, ar, kbox[r], karea[r]);
                done = d2;
                if ((int)(u32)pk >= j - 2) break;        // coverage fresh enough
                __builtin_amdgcn_s_sleep(1);
                pk = aload64(progcnt);
            }
            u64 ksf = __ballot(sup);
            if (lane == 0) {
                KS[slot] = ksf; KBa[slot] = (u32)(pk >> 32);
                __hip_atomic_store(&flagIK32[slot * 2], (u32)(j + 1), __ATOMIC_RELEASE, WG);
            }
            if ((u32)pk >= DONEP) return;
        }
        return;
    }

    // ======= wave 0: serial scan (prio 3; shares SIMD with 1 wave) =======
    __builtin_amdgcn_s_setprio(3);
    int kept = 0; u32 kcur = 0; bool capped = false;
    u16 key = (nch > 0) ? sc_[lane] : (u16)0xFFFF;       // chunk-0 prefetch
    for (int k = 0; k < nch; ++k) {
        const int slot = k & (SLOTS - 1);
        bool valid = (key != 0xFFFF);
        u32 j = valid ? key : 0u;

        const u64 want = ((u64)(u32)(k + 1) << 32) | (u32)(k + 1);
        while (aload64(&flagIK[slot]) != want) { }        // both flags, one poll
        u64 ks = KS[slot];
        u32 kb = KBa[slot];
        float4 bx = Bring[slot * 64 + lane];
        u64 I = Iring[slot * 64 + lane];
        if (ks != ~0ull) {
            float ar = (bx.z - bx.x) * (bx.w - bx.y);
            bool alive = valid && !((ks >> lane) & 1ull);
            u32 r1 = (kcur + 3) & ~3u;                    // own writes: race-free
            for (u32 r = kb & ~3u; r < r1; r += 4) {
                float4 q0 = kbox[r], q1 = kbox[r + 1], q2 = kbox[r + 2], q3 = kbox[r + 3];
                float4 a4 = *(const float4*)(karea + r);
                bool s = iou3(bx, ar, q0, a4.x) | iou3(bx, ar, q1, a4.y)
                       | iou3(bx, ar, q2, a4.z) | iou3(bx, ar, q3, a4.w);
                alive = alive && !s;
            }
            u64 rem = __ballot(alive);
            if (rem) {
                u64 km = 0ull;
                while (rem) {                             // SALU keep chain
                    int pos = __ffsll((long long)rem) - 1;
                    km |= 1ull << pos;
                    if (++kept == MAX_BOXES) { capped = true; break; }
                    u32 lo = (u32)__builtin_amdgcn_readlane((int)(u32)I, pos);
                    u32 hi = (u32)__builtin_amdgcn_readlane((int)(u32)(I >> 32), pos);
                    rem &= ~(((u64)hi << 32) | (u64)lo);  // diag bit kills pos
                }
                if ((km >> lane) & 1ull) {
                    int rank = (int)__popcll(km & ((1ull << lane) - 1ull));
                    kbox[kcur + rank] = bx;
                    karea[kcur + rank] = ar;
                    kout16[kcur + rank] = (u16)j;
                }
                kcur += (u32)__popcll(km);
            }
        }
        if (capped) break;
        if (lane == 0)                                    // single packed release
            __hip_atomic_store(progcnt, ((u64)kcur << 32) | (u32)(k + 1),
                               __ATOMIC_RELEASE, WG);
        if (k + 1 < nch) key = sc_[(k + 1) * 64 + lane];  // prefetch next chunk
    }
    if (lane == 0)
        __hip_atomic_store(progcnt, ((u64)kcur << 32) | DONEP, __ATOMIC_RELEASE, WG);
    __builtin_amdgcn_s_setprio(0);

    // flush: gather scores for kept anchors only (~kcur per class)
    for (u32 i = (u32)lane; i < kcur; i += 64) {
        u32 idx = kout16[i];
        out[(size_t)idx * OUT_COLS + 4 + c] = cls[(size_t)idx * N_CLASSES + c];
    }
}

extern "C" void kernel_launch(void* const* d_in, const int* in_sizes, int n_in,
                              void* d_out, int out_size, void* d_ws, size_t ws_size,
                              hipStream_t stream) {
    const float* boxes = (const float*)d_in[0];
    const float* cls   = (const float*)d_in[1];
    float* out = (float*)d_out;
    u16* sidx   = (u16*)d_ws;                                  // 0.82 MB
    u32* totals = (u32*)((char*)d_ws + N_CLASSES * SIDX_PAD * 2);
    nms_sort<<<N_CLASSES, 1024, 0, stream>>>(cls, boxes, out, sidx, totals);
    nms_scan<<<N_CLASSES, 512, 0, stream>>>(cls, (const float4*)boxes, sidx, totals, out);
}

// Round 9
// 141.316 us; speedup vs baseline: 1.0543x; 1.0232x over previous
//
#include <hip/hip_runtime.h>

#define N_ANCHORS 5000
#define N_CLASSES 80
#define OUT_COLS  84
#define MAX_BOXES 300
#define SCORE_THR 0.05f

#define SORT_PAD  5056
#define SIDX_PAD  5120
#define NB        4096
#define SLOTS     8
#define DONEP     0x40000000
#define NIW       2            // scan: intra workers wv 1..2
#define NSW       5            // scan: sweeps wv 3..7

typedef unsigned long long u64;
typedef unsigned int u32;
typedef unsigned short u16;

#define WG __HIP_MEMORY_SCOPE_WORKGROUP
// hist index padding: breaks the stride-4 8-way bank conflict
#define HP(b) ((b) + ((b) >> 5))

__device__ __forceinline__ float readlane_f(float v, int l) {
    return __int_as_float(__builtin_amdgcn_readlane(__float_as_int(v), l));
}
__device__ __forceinline__ u64 aload64(u64* p) {
    return __hip_atomic_load(p, __ATOMIC_ACQUIRE, WG);
}
// monotone score->bucket map; mirrored so chunk 0 = HIGHEST scores
__device__ __forceinline__ int bucket_of(float s) {
    float u = sqrtf(s);
    int b = (int)((u - 0.2236f) * 5275.0f);
    return (NB - 1) - min(max(b, 0), NB - 1);
}
// IoU(a,q) > 0.5  <=>  3*inter > aa+aq.  Single clamp: all real areas >= 1
// so aa+aq > 0; if ih < 0 then iw_cl*ih <= 0 < aa+aq -> false.  Sentinel q
// (1e9 coords, karea 1e18) -> false.
__device__ __forceinline__ bool iou3(float4 a, float aa, float4 q, float aq) {
    float iw = fmaxf(fminf(a.z, q.z) - fmaxf(a.x, q.x), 0.0f);
    float ih = fminf(a.w, q.w) - fmaxf(a.y, q.y);
    return 3.0f * (iw * ih) > aa + aq;
}

// ============ dispatch 1: prep + bucket sort -> workspace ============
// Typed __shared__ (no generic-pointer casts): guarantees ds_* codegen.
__global__ __launch_bounds__(1024) void nms_sort(const float* __restrict__ cls,
                                                 const float* __restrict__ boxesf,
                                                 float* __restrict__ out,
                                                 u16* __restrict__ sidx,
                                                 u32* __restrict__ totals) {
    __shared__ __align__(16) u64 lk[SORT_PAD];
    __shared__ u32 hist[4224];
    __shared__ u32 wtot[16];

    const int c = blockIdx.x;
    const int t = threadIdx.x;
    const int lane = t & 63;
    const int wv = t >> 6;

    // strided score loads (cls L2-resident; each line feeds 16 class-blocks)
    u32 sb[5];
    #pragma unroll
    for (int m = 0; m < 5; ++m) {
        int j = m * 1024 + t;
        float v = (j < N_ANCHORS) ? cls[(size_t)j * N_CLASSES + c] : 0.0f;
        sb[m] = (v > SCORE_THR) ? __float_as_uint(v) : 0u;
    }
    // coalesced full-row out init: block c owns rows [c*63, c*63+63)
    {
        const int r0 = c * 63;
        const int rend = min(r0 + 63, N_ANCHORS);
        const int nel = (rend - r0) * OUT_COLS;
        float* ob = out + (size_t)r0 * OUT_COLS;
        for (int i = t; i < nel; i += 1024) {
            int row = r0 + i / OUT_COLS;
            int col = i - (i / OUT_COLS) * OUT_COLS;
            ob[i] = (col < 4) ? boxesf[(size_t)row * 4 + col] : 0.0f;
        }
    }

    for (int b = t; b < HP(NB - 1) + 1; b += 1024) hist[b] = 0u;
    __syncthreads();
    #pragma unroll
    for (int m = 0; m < 5; ++m)
        if (sb[m]) atomicAdd(&hist[HP(bucket_of(__uint_as_float(sb[m])))], 1u);
    __syncthreads();

    const int hbase = t * 4;
    u32 vals[4]; u32 run = 0;
    #pragma unroll
    for (int k = 0; k < 4; ++k) { run += hist[HP(hbase + k)]; vals[k] = run; }
    u32 x = run;
    #pragma unroll
    for (int off = 1; off < 64; off <<= 1) { u32 y = __shfl_up(x, off); if (lane >= off) x += y; }
    if (lane == 63) wtot[wv] = x;
    __syncthreads();
    u32 woff = 0;
    for (int w = 0; w < wv; ++w) woff += wtot[w];
    const u32 exb = woff + x - run;
    #pragma unroll
    for (int k = 0; k < 4; ++k) hist[HP(hbase + k)] = exb + (k ? vals[k - 1] : 0u);
    __syncthreads();
    #pragma unroll
    for (int m = 0; m < 5; ++m) {
        if (sb[m]) {
            int j = m * 1024 + t;
            u32 pos = atomicAdd(&hist[HP(bucket_of(__uint_as_float(sb[m])))], 1u);
            lk[pos] = ((u64)sb[m] << 32) | (u32)(~(u32)j);
        }
    }
    __syncthreads();
    const int total = (int)hist[HP(NB - 1)];
    for (int v = total + t; v < SORT_PAD; v += 1024) lk[v] = 0ull;
    for (int b = hbase; b < hbase + 4; ++b) {
        int s0 = b ? (int)hist[HP(b - 1)] : 0;
        int e  = (int)hist[HP(b)];
        for (int i = s0 + 1; i < e; ++i) {
            u64 key = lk[i]; int q = i - 1;
            while (q >= s0 && lk[q] < key) { lk[q + 1] = lk[q]; --q; }
            lk[q + 1] = key;
        }
    }
    __syncthreads();
    // export sorted anchor indices (u16, 0xFFFF sentinel)
    u16* sc_ = sidx + (size_t)c * SIDX_PAD;
    for (int v = t; v < SIDX_PAD; v += 1024) {
        u64 e = (v < SORT_PAD) ? lk[v] : 0ull;
        sc_[v] = e ? (u16)(~(u32)e) : (u16)0xFFFF;
    }
    if (t == 0) totals[c] = (u32)total;
}

// ============ dispatch 2: pipelined scan (8 waves: 1 serial + 2 intra + 5 sweep) ============
// Typed __shared__ arrays — protocol identical to previous round.
__global__ __launch_bounds__(512, 1) void nms_scan(const float* __restrict__ cls,
                                                   const float4* __restrict__ boxes4,
                                                   const u16* __restrict__ sidx,
                                                   const u32* __restrict__ totals,
                                                   float* __restrict__ out) {
    __shared__ u64 Iring[SLOTS * 64];
    __shared__ float4 Bring[SLOTS * 64];
    __shared__ float4 kbox[304];                 // sentinel-padded
    __shared__ __align__(16) float karea[304];   // kept areas, sentinel 1e18
    __shared__ u16 kout16[304];
    __shared__ u64 KS[SLOTS];
    __shared__ u32 KBa[SLOTS];
    __shared__ u64 flagIK[SLOTS];                // {lo=flagK, hi=flagI}
    __shared__ u64 progcnt;                      // {lo=prog, hi=kcnt}
    u32* flagIK32 = (u32*)flagIK;

    const int c = blockIdx.x;
    const int t = threadIdx.x;
    const int lane = t & 63;
    const int wv = t >> 6;
    const u16* sc_ = sidx + (size_t)c * SIDX_PAD;

    if (t < 304) { kbox[t] = make_float4(1e9f, 1e9f, 1e9f, 1e9f); karea[t] = 1e18f; }
    if (t < SLOTS) flagIK[t] = 0ull;
    if (t == 0) progcnt = 0ull;
    __syncthreads();
    const int total = (int)totals[c];
    const int nch = (total + 63) >> 6;

    if (wv >= 1 && wv <= NIW) {
        // ======= intra workers: 64x64 IoU matrix; compute PRE-gate =======
        for (int j = wv - 1; j < nch; j += NIW) {
            const int slot = j & (SLOTS - 1);
            u16 g = sc_[j * 64 + lane];
            u32 jj = (g != 0xFFFF) ? g : 0u;
            float4 bx = boxes4[jj];
            float ar = (bx.z - bx.x) * (bx.w - bx.y);
            u64 word = 0ull;
            #pragma unroll 16
            for (int q = 0; q < 64; ++q) {
                float4 o;
                o.x = readlane_f(bx.x, q); o.y = readlane_f(bx.y, q);
                o.z = readlane_f(bx.z, q); o.w = readlane_f(bx.w, q);
                float aq = readlane_f(ar, q);
                float iw = fmaxf(fminf(bx.z, o.z) - fmaxf(bx.x, o.x), 0.0f);
                float ih = fminf(bx.w, o.w) - fmaxf(bx.y, o.y);
                if (3.0f * (iw * ih) > ar + aq) word |= (1ull << q);
            }
            u32 p;
            for (;;) {                                   // gate guards the store only
                p = (u32)aload64(&progcnt);
                if ((int)p >= j - (SLOTS - 1)) break;
                __builtin_amdgcn_s_sleep(2);
            }
            if (p >= DONEP) return;
            Iring[slot * 64 + lane] = word;
            if (lane == 0)
                __hip_atomic_store(&flagIK32[slot * 2 + 1], (u32)(j + 1), __ATOMIC_RELEASE, WG);
        }
        return;
    }
    if (wv > NIW) {
        // ======= sweeps: 8-keep unrolled batched-load kept-scan =======
        for (int j = wv - (NIW + 1); j < nch; j += NSW) {
            const int slot = j & (SLOTS - 1);
            u16 g = sc_[j * 64 + lane];
            bool validL = (g != 0xFFFF);
            u32 jj = validL ? g : 0u;
            float4 bx = boxes4[jj];
            float ar = (bx.z - bx.x) * (bx.w - bx.y);
            u64 pk;
            for (;;) {                                   // slot-free gate
                pk = aload64(&progcnt);
                if ((int)(u32)pk >= j - (SLOTS - 1)) break;
                __builtin_amdgcn_s_sleep(2);
            }
            if ((u32)pk >= DONEP) return;
            Bring[slot * 64 + lane] = bx;
            bool sup = !validL;                          // invalid = suppressed
            u32 done = 0; bool alldead = false;
            for (;;) {
                u32 kn = (u32)(pk >> 32);
                u32 r8 = kn & ~7u;                       // bulk rounds DOWN: only
                for (u32 r = done; r < r8; r += 8) {     // published entries read
                    float4 q0 = kbox[r+0], q1 = kbox[r+1], q2 = kbox[r+2], q3 = kbox[r+3];
                    float4 q4 = kbox[r+4], q5 = kbox[r+5], q6 = kbox[r+6], q7 = kbox[r+7];
                    float4 a40 = *(const float4*)(karea + r);
                    float4 a41 = *(const float4*)(karea + r + 4);
                    sup = sup | iou3(bx,ar,q0,a40.x) | iou3(bx,ar,q1,a40.y)
                              | iou3(bx,ar,q2,a40.z) | iou3(bx,ar,q3,a40.w)
                              | iou3(bx,ar,q4,a41.x) | iou3(bx,ar,q5,a41.y)
                              | iou3(bx,ar,q6,a41.z) | iou3(bx,ar,q7,a41.w);
                    if (((r >> 3) & 3u) == 3u && !__ballot(!sup)) { alldead = true; break; }
                }
                if (alldead) break;
                u32 d2 = (r8 > done) ? r8 : done;
                for (u32 r = d2; r < kn; ++r)            // <=7 published remainder
                    sup = sup | iou3(bx, ar, kbox[r], karea[r]);
                done = d2;
                if ((int)(u32)pk >= j - 2) break;        // coverage fresh enough
                __builtin_amdgcn_s_sleep(1);
                pk = aload64(&progcnt);
            }
            u64 ksf = __ballot(sup);
            if (lane == 0) {
                KS[slot] = ksf; KBa[slot] = (u32)(pk >> 32);
                __hip_atomic_store(&flagIK32[slot * 2], (u32)(j + 1), __ATOMIC_RELEASE, WG);
            }
            if ((u32)pk >= DONEP) return;
        }
        return;
    }

    // ======= wave 0: serial scan (prio 3; shares SIMD with 1 wave) =======
    __builtin_amdgcn_s_setprio(3);
    int kept = 0; u32 kcur = 0; bool capped = false;
    u16 key = (nch > 0) ? sc_[lane] : (u16)0xFFFF;       // chunk-0 prefetch
    for (int k = 0; k < nch; ++k) {
        const int slot = k & (SLOTS - 1);
        bool valid = (key != 0xFFFF);
        u32 j = valid ? key : 0u;

        const u64 want = ((u64)(u32)(k + 1) << 32) | (u32)(k + 1);
        while (aload64(&flagIK[slot]) != want) { }        // both flags, one poll
        u64 ks = KS[slot];
        u32 kb = KBa[slot];
        float4 bx = Bring[slot * 64 + lane];
        u64 I = Iring[slot * 64 + lane];
        if (ks != ~0ull) {
            float ar = (bx.z - bx.x) * (bx.w - bx.y);
            bool alive = valid && !((ks >> lane) & 1ull);
            u32 r1 = (kcur + 3) & ~3u;                    // own writes: race-free
            for (u32 r = kb & ~3u; r < r1; r += 4) {
                float4 q0 = kbox[r], q1 = kbox[r + 1], q2 = kbox[r + 2], q3 = kbox[r + 3];
                float4 a4 = *(const float4*)(karea + r);
                bool s = iou3(bx, ar, q0, a4.x) | iou3(bx, ar, q1, a4.y)
                       | iou3(bx, ar, q2, a4.z) | iou3(bx, ar, q3, a4.w);
                alive = alive && !s;
            }
            u64 rem = __ballot(alive);
            if (rem) {
                u64 km = 0ull;
                while (rem) {                             // SALU keep chain
                    int pos = __ffsll((long long)rem) - 1;
                    km |= 1ull << pos;
                    if (++kept == MAX_BOXES) { capped = true; break; }
                    u32 lo = (u32)__builtin_amdgcn_readlane((int)(u32)I, pos);
                    u32 hi = (u32)__builtin_amdgcn_readlane((int)(u32)(I >> 32), pos);
                    rem &= ~(((u64)hi << 32) | (u64)lo);  // diag bit kills pos
                }
                if ((km >> lane) & 1ull) {
                    int rank = (int)__popcll(km & ((1ull << lane) - 1ull));
                    kbox[kcur + rank] = bx;
                    karea[kcur + rank] = ar;
                    kout16[kcur + rank] = (u16)j;
                }
                kcur += (u32)__popcll(km);
            }
        }
        if (capped) break;
        if (lane == 0)                                    // single packed release
            __hip_atomic_store(&progcnt, ((u64)kcur << 32) | (u32)(k + 1),
                               __ATOMIC_RELEASE, WG);
        if (k + 1 < nch) key = sc_[(k + 1) * 64 + lane];  // prefetch next chunk
    }
    if (lane == 0)
        __hip_atomic_store(&progcnt, ((u64)kcur << 32) | DONEP, __ATOMIC_RELEASE, WG);
    __builtin_amdgcn_s_setprio(0);

    // flush: gather scores for kept anchors only (~kcur per class)
    for (u32 i = (u32)lane; i < kcur; i += 64) {
        u32 idx = kout16[i];
        out[(size_t)idx * OUT_COLS + 4 + c] = cls[(size_t)idx * N_CLASSES + c];
    }
}

extern "C" void kernel_launch(void* const* d_in, const int* in_sizes, int n_in,
                              void* d_out, int out_size, void* d_ws, size_t ws_size,
                              hipStream_t stream) {
    const float* boxes = (const float*)d_in[0];
    const float* cls   = (const float*)d_in[1];
    float* out = (float*)d_out;
    u16* sidx   = (u16*)d_ws;                                  // 0.82 MB
    u32* totals = (u32*)((char*)d_ws + N_CLASSES * SIDX_PAD * 2);
    nms_sort<<<N_CLASSES, 1024, 0, stream>>>(cls, boxes, out, sidx, totals);
    nms_scan<<<N_CLASSES, 512, 0, stream>>>(cls, (const float4*)boxes, sidx, totals, out);
}